// Round 19
// baseline (300.147 us; speedup 1.0000x reference)
//
#include <hip/hip_runtime.h>

typedef unsigned short u16;
typedef __attribute__((ext_vector_type(8))) short short8;
typedef __attribute__((ext_vector_type(4))) float f32x4;
typedef __attribute__((ext_vector_type(4))) u16 u16x4;

#define MFMA16(a, b, c) __builtin_amdgcn_mfma_f32_16x16x32_bf16(a, b, c, 0, 0, 0)
#define EXP2(x) __builtin_amdgcn_exp2f(x)

#define LOG2E 1.4426950408889634f
// q-side fold: (1/sqrt(32)) * log2(e)
#define QSCALE 0.25506038410312156f

__device__ __forceinline__ u16 f2bf(float f) {
    unsigned int u = __builtin_bit_cast(unsigned int, f);
    u += 0x7fffu + ((u >> 16) & 1u);
    return (u16)(u >> 16);
}

// ---------------------------------------------------------------------------
// repack: weights -> bf16 transposed [N][K]; q-weights pre-scaled by QSCALE
// ---------------------------------------------------------------------------
__global__ __launch_bounds__(256) void repack_kernel(
    const float* __restrict__ wq, const float* __restrict__ wk, const float* __restrict__ wv,
    const float* __restrict__ bq, const float* __restrict__ bk, const float* __restrict__ bv,
    const float* __restrict__ w1, const float* __restrict__ w2,
    u16* __restrict__ wqkvT, u16* __restrict__ w1T, u16* __restrict__ w2T,
    float* __restrict__ bqkv)
{
    long idx = (long)blockIdx.x * 256 + threadIdx.x;
    const long NQ = 4L * 768 * 256;
    const long N1 = 4L * 512 * 256;
    const long N2 = 4L * 256 * 512;
    const long NB = 4L * 768;
    if (idx < NQ) {
        long l = idx / (768 * 256); long r = idx % (768 * 256);
        long n = r / 256, k = r % 256;
        float v;
        if (n < 256)      v = wq[(l * 256 + k) * 256 + n] * QSCALE;
        else if (n < 512) v = wk[(l * 256 + k) * 256 + (n - 256)];
        else              v = wv[(l * 256 + k) * 256 + (n - 512)];
        wqkvT[idx] = f2bf(v);
    } else if ((idx -= NQ) < N1) {
        long l = idx / (512 * 256); long r = idx % (512 * 256);
        long n = r / 256, k = r % 256;
        w1T[idx] = f2bf(w1[(l * 256 + k) * 512 + n]);
    } else if ((idx -= N1) < N2) {
        long l = idx / (256 * 512); long r = idx % (256 * 512);
        long n = r / 512, k = r % 512;
        w2T[idx] = f2bf(w2[(l * 512 + k) * 256 + n]);
    } else if ((idx -= N2) < NB) {
        long l = idx / 768; long n = idx % 768;
        float v = (n < 256) ? bq[l * 256 + n] * QSCALE
                : (n < 512) ? bk[l * 256 + (n - 256)]
                            : bv[l * 256 + (n - 512)];
        bqkv[l * 768 + n] = v;
    }
}

// ---------------------------------------------------------------------------
// x convert: fp32 master + bf16 copy; also build kcoord rows (layer-indep):
// kcoord[b][n][32] bf16 = {LOG2E*c0, LOG2E*c1, LOG2E*c2, 0...} (zero-padded)
// ---------------------------------------------------------------------------
__global__ __launch_bounds__(256) void xconv_kernel(
    const float* __restrict__ xin, const float* __restrict__ coords,
    float* __restrict__ xf, u16* __restrict__ xb, u16* __restrict__ kcoord)
{
    long idx = (long)blockIdx.x * 256 + threadIdx.x;
    if (idx < 4096L * 256) {
        float v = xin[idx];
        xf[idx] = v;
        xb[idx] = f2bf(v);
    }
    if (idx < 4096) {
        const float* c = coords + idx * 3;
        u16 r0 = f2bf(c[0] * LOG2E), r1 = f2bf(c[1] * LOG2E), r2 = f2bf(c[2] * LOG2E);
        uint4 lo; lo.x = (unsigned)r0 | ((unsigned)r1 << 16); lo.y = (unsigned)r2; lo.z = 0; lo.w = 0;
        uint4 z4; z4.x = 0; z4.y = 0; z4.z = 0; z4.w = 0;
        uint4* dst = (uint4*)(kcoord + idx * 32);
        dst[0] = lo; dst[1] = z4; dst[2] = z4; dst[3] = z4;
    }
}

// ---------------------------------------------------------------------------
// QKV GEMM: A[4096,256]@BT[768,256]^T + bias -> packed per-head outputs:
//   qt/kt[bh][2048][32], vt[bh][32][2048]   (bh = b*8+h)
// Wave tile 32x64 (2x4 frags, 6 loads : 8 MFMA). Block 64x128. Grid (64,6).
// ---------------------------------------------------------------------------
__global__ __launch_bounds__(256) void qkvgemm_kernel(
    const u16* __restrict__ A, const u16* __restrict__ BT,
    const float* __restrict__ bias,
    u16* __restrict__ qt, u16* __restrict__ kt, u16* __restrict__ vt)
{
    const int K = 256;
    int w = threadIdx.x >> 6, lane = threadIdx.x & 63;
    int wr = w >> 1, wc = w & 1;
    int m0 = blockIdx.x * 64 + wr * 32;
    int n0 = blockIdx.y * 128 + wc * 64;
    int l16 = lane & 15, lhi = lane >> 4;

    f32x4 acc[2][4];
#pragma unroll
    for (int i = 0; i < 2; i++)
#pragma unroll
        for (int j = 0; j < 4; j++) acc[i][j] = (f32x4){0.f, 0.f, 0.f, 0.f};

    const u16* Ap = A + (size_t)(m0 + l16) * K + lhi * 8;
    const u16* Bp = BT + (size_t)(n0 + l16) * K + lhi * 8;

#pragma unroll 4
    for (int k = 0; k < K; k += 32) {
        short8 a0 = *(const short8*)(Ap + k);
        short8 a1 = *(const short8*)(Ap + (size_t)16 * K + k);
        short8 b[4];
#pragma unroll
        for (int j = 0; j < 4; j++) b[j] = *(const short8*)(Bp + (size_t)(j * 16) * K + k);
#pragma unroll
        for (int j = 0; j < 4; j++) {
            acc[0][j] = MFMA16(a0, b[j], acc[0][j]);
            acc[1][j] = MFMA16(a1, b[j], acc[1][j]);
        }
    }

#pragma unroll
    for (int i = 0; i < 2; i++)
#pragma unroll
        for (int j = 0; j < 4; j++) {
            int n = n0 + j * 16 + l16;
            float bs = bias[n];
            int sect = n >> 8;          // 0:q 1:k 2:v
            int h = (n >> 5) & 7;
            int d = n & 31;
            int m = m0 + i * 16 + lhi * 4;
            int b_ = m >> 11, mseq = m & 2047;
            if (sect < 2) {
                u16* dst = (sect == 0 ? qt : kt) + ((size_t)(b_ * 8 + h) * 2048 + mseq) * 32 + d;
#pragma unroll
                for (int r = 0; r < 4; r++) dst[(size_t)r * 32] = f2bf(acc[i][j][r] + bs);
            } else {
                u16x4 pk;
#pragma unroll
                for (int r = 0; r < 4; r++) pk[r] = f2bf(acc[i][j][r] + bs);
                *(u16x4*)(vt + ((size_t)(b_ * 8 + h) * 32 + d) * 2048 + mseq) = pk;
            }
        }
}

// ---------------------------------------------------------------------------
// FFN1 GEMM: relu(A@BT^T + bias), bf16 out. Wave 32x64, block 64x128.
// Grid (64, 4) for N=512.
// ---------------------------------------------------------------------------
__global__ __launch_bounds__(256) void gemm_relu_kernel(
    const u16* __restrict__ A, const u16* __restrict__ BT,
    const float* __restrict__ bias, u16* __restrict__ outp,
    int M, int N, int K)
{
    int w = threadIdx.x >> 6, lane = threadIdx.x & 63;
    int wr = w >> 1, wc = w & 1;
    int m0 = blockIdx.x * 64 + wr * 32;
    int n0 = blockIdx.y * 128 + wc * 64;
    int l16 = lane & 15, lhi = lane >> 4;

    f32x4 acc[2][4];
#pragma unroll
    for (int i = 0; i < 2; i++)
#pragma unroll
        for (int j = 0; j < 4; j++) acc[i][j] = (f32x4){0.f, 0.f, 0.f, 0.f};

    const u16* Ap = A + (size_t)(m0 + l16) * K + lhi * 8;
    const u16* Bp = BT + (size_t)(n0 + l16) * K + lhi * 8;

#pragma unroll 4
    for (int k = 0; k < K; k += 32) {
        short8 a0 = *(const short8*)(Ap + k);
        short8 a1 = *(const short8*)(Ap + (size_t)16 * K + k);
        short8 b[4];
#pragma unroll
        for (int j = 0; j < 4; j++) b[j] = *(const short8*)(Bp + (size_t)(j * 16) * K + k);
#pragma unroll
        for (int j = 0; j < 4; j++) {
            acc[0][j] = MFMA16(a0, b[j], acc[0][j]);
            acc[1][j] = MFMA16(a1, b[j], acc[1][j]);
        }
    }

#pragma unroll
    for (int i = 0; i < 2; i++)
#pragma unroll
        for (int j = 0; j < 4; j++) {
            int n = n0 + j * 16 + l16;
            float bs = bias[n];
#pragma unroll
            for (int r = 0; r < 4; r++) {
                int m = m0 + i * 16 + lhi * 4 + r;
                outp[(size_t)m * N + n] = f2bf(fmaxf(acc[i][j][r] + bs, 0.f));
            }
        }
}

// ---------------------------------------------------------------------------
// FFN2 GEMM: C = A@BT^T + bias, f32 out. Block 64x64 (4 waves 32x32).
// ---------------------------------------------------------------------------
__global__ __launch_bounds__(256) void gemm_f32_kernel(
    const u16* __restrict__ A, const u16* __restrict__ BT,
    const float* __restrict__ bias, float* __restrict__ outp,
    int M, int N, int K)
{
    int w = threadIdx.x >> 6, lane = threadIdx.x & 63;
    int wr = w >> 1, wc = w & 1;
    int m0 = blockIdx.x * 64 + wr * 32;
    int n0 = blockIdx.y * 64 + wc * 32;
    int l16 = lane & 15, lhi = lane >> 4;

    f32x4 acc[2][2];
#pragma unroll
    for (int i = 0; i < 2; i++)
#pragma unroll
        for (int j = 0; j < 2; j++) acc[i][j] = (f32x4){0.f, 0.f, 0.f, 0.f};

    const u16* Ap = A + (size_t)(m0 + l16) * K + lhi * 8;
    const u16* Bp = BT + (size_t)(n0 + l16) * K + lhi * 8;

#pragma unroll 4
    for (int k = 0; k < K; k += 32) {
        short8 a0 = *(const short8*)(Ap + k);
        short8 a1 = *(const short8*)(Ap + (size_t)16 * K + k);
        short8 b0 = *(const short8*)(Bp + k);
        short8 b1 = *(const short8*)(Bp + (size_t)16 * K + k);
        acc[0][0] = MFMA16(a0, b0, acc[0][0]);
        acc[0][1] = MFMA16(a0, b1, acc[0][1]);
        acc[1][0] = MFMA16(a1, b0, acc[1][0]);
        acc[1][1] = MFMA16(a1, b1, acc[1][1]);
    }

#pragma unroll
    for (int i = 0; i < 2; i++)
#pragma unroll
        for (int j = 0; j < 2; j++) {
            int n = n0 + j * 16 + l16;
            float bs = bias[n];
#pragma unroll
            for (int r = 0; r < 4; r++) {
                int m = m0 + i * 16 + lhi * 4 + r;
                outp[(size_t)m * N + n] = acc[i][j][r] + bs;
            }
        }
}

// ---------------------------------------------------------------------------
// Flash attention, 4 Q-fragments (64 q-rows/block) sharing every K/khi/V
// load: 48 MFMAs per 12-load round. Grid 1024 = 16 bh x 32 qtiles x 2
// kvhalf -> 4 blocks/CU (38KB LDS), whole grid resident. s_setprio(1)
// around MFMA clusters (T5): 4 waves/SIMD at independent phases.
// ---------------------------------------------------------------------------
__global__ __launch_bounds__(256, 2) void attn_kernel(
    const u16* __restrict__ qt, const u16* __restrict__ kt, const u16* __restrict__ vt,
    const u16* __restrict__ kcoord, const float* __restrict__ coords,
    const float* __restrict__ alpha, int layer,
    float* __restrict__ po, float* __restrict__ pml)
{
    int tid = threadIdx.x;
    int w = tid >> 6, lane = tid & 63;
    int flat = blockIdx.x;
    int bh = (flat & 7) | (((flat >> 3) & 1) << 3);
    int b = bh >> 3, h = bh & 7;
    int m0 = ((flat >> 4) & 31) * 64;
    int kvhalf = flat >> 9;
    int l16 = lane & 15, lhi = lane >> 4;

    // smem: [0,32768) = per-(wave,qq) P buffers u16[16][1024] (2KB each),
    //       aliased post-barrier as float olds[16][16][36] (36864 B)
    //       [36864, 38912) = float mlds[16][2][16]
    __shared__ __align__(16) char smem[36864 + 2048];
    float* olds = (float*)smem;
    float* mlds = (float*)(smem + 36864);
    u16* plbase = (u16*)smem;

    const u16* qbase = qt + (size_t)bh * 2048 * 32;
    float al = alpha[layer];
    short8 qlo[4], qhi[4];
#pragma unroll
    for (int qq = 0; qq < 4; qq++) {
        qlo[qq] = *(const short8*)(qbase + (size_t)(m0 + qq * 16 + l16) * 32 + lhi * 8);
        short8 z = {0, 0, 0, 0, 0, 0, 0, 0};
        qhi[qq] = z;
        if (lhi == 0) {
            const float* c = coords + (size_t)(b * 2048 + m0 + qq * 16 + l16) * 3;
            qhi[qq][0] = (short)f2bf(c[0] * al);
            qhi[qq][1] = (short)f2bf(c[1] * al);
            qhi[qq][2] = (short)f2bf(c[2] * al);
        }
    }

    f32x4 oacc[4][2];
#pragma unroll
    for (int qq = 0; qq < 4; qq++)
#pragma unroll
        for (int dt = 0; dt < 2; dt++) oacc[qq][dt] = (f32x4){0.f, 0.f, 0.f, 0.f};
    float mrow[4] = {-1e30f, -1e30f, -1e30f, -1e30f};
    float lrow[4] = {0.f, 0.f, 0.f, 0.f};

    int nstart = kvhalf * 1024 + w * 256;   // 256 KV cols per wave = 4 x 64

    unsigned kidx = ((unsigned)(bh * 2048 + nstart + l16) << 5) + lhi * 8;
    unsigned cidx = ((unsigned)(b * 2048 + nstart + l16) << 5) + lhi * 8;
    unsigned vidxA = ((unsigned)(bh * 32 + l16) << 11) + nstart + lhi * 8;
    unsigned vidxB = vidxA + (16u << 11);

    int hb = lhi >> 1, s7 = l16 & 7, lo4 = (lhi & 1) * 4;
    int wb = l16 * 64;
    int wa[4], ra[2];
#pragma unroll
    for (int t = 0; t < 4; t++) wa[t] = wb + (((((t << 1) | hb)) ^ s7) << 3) + lo4;
#pragma unroll
    for (int kk = 0; kk < 2; kk++) ra[kk] = wb + ((((kk << 2) | lhi) ^ s7) << 3);

    u16* plw = plbase + w * 4096;           // 4 qq buffers of 1024 u16 each

#pragma unroll
    for (int nbi = 0; nbi < 4; nbi++) {
        // tile loads (shared across all 4 Q-fragments)
        short8 klo[4], khi[4];
#pragma unroll
        for (int t = 0; t < 4; t++) klo[t] = *(const short8*)(kt + kidx + t * 512);
#pragma unroll
        for (int t = 0; t < 4; t++) khi[t] = *(const short8*)(kcoord + cidx + t * 512);
        kidx += 2048; cidx += 2048;
        short8 v0a = *(const short8*)(vt + vidxA);
        short8 v0b = *(const short8*)(vt + vidxA + 32);
        short8 v1a = *(const short8*)(vt + vidxB);
        short8 v1b = *(const short8*)(vt + vidxB + 32);
        vidxA += 64; vidxB += 64;

#pragma unroll
        for (int qq = 0; qq < 4; qq++) {
            f32x4 s[4];
            __builtin_amdgcn_s_setprio(1);
#pragma unroll
            for (int t = 0; t < 4; t++) {
                f32x4 z = (f32x4){0.f, 0.f, 0.f, 0.f};
                z = MFMA16(klo[t], qlo[qq], z);
                s[t] = MFMA16(khi[t], qhi[qq], z);
            }
            __builtin_amdgcn_s_setprio(0);
            float lm = -1e30f;
#pragma unroll
            for (int t = 0; t < 4; t++) {
                float a = fmaxf(fmaxf(s[t][0], s[t][1]), fmaxf(s[t][2], s[t][3]));
                lm = fmaxf(lm, a);
            }
            if (!__all(lm <= mrow[qq] + 8.f)) {
                float tm = fmaxf(lm, __shfl_xor(lm, 16, 64));
                tm = fmaxf(tm, __shfl_xor(tm, 32, 64));
                float mnew = fmaxf(mrow[qq], tm);
                float corr = EXP2(mrow[qq] - mnew);
                mrow[qq] = mnew;
#pragma unroll
                for (int dt = 0; dt < 2; dt++)
#pragma unroll
                    for (int r = 0; r < 4; r++) oacc[qq][dt][r] *= corr;
                lrow[qq] *= corr;
            }

            float rs = 0.f;
#pragma unroll
            for (int t = 0; t < 4; t++) {
#pragma unroll
                for (int r = 0; r < 4; r++) s[t][r] = EXP2(s[t][r] - mrow[qq]);
                rs += (s[t][0] + s[t][1]) + (s[t][2] + s[t][3]);
            }
            lrow[qq] += rs;  // per-lane partial; cross-lane reduce at wave end

            u16* pl = plw + qq * 1024;
#pragma unroll
            for (int t = 0; t < 4; t++) {
                unsigned p0, p1;
                asm("v_cvt_pk_bf16_f32 %0, %1, %2" : "=v"(p0) : "v"(s[t][0]), "v"(s[t][1]));
                asm("v_cvt_pk_bf16_f32 %0, %1, %2" : "=v"(p1) : "v"(s[t][2]), "v"(s[t][3]));
                uint2 val; val.x = p0; val.y = p1;
                *(uint2*)(pl + wa[t]) = val;
            }
        }

        // PV: out^T[d][q] += V^T[d][n] * P^T[n][q]; V shared across qq
        __builtin_amdgcn_s_setprio(1);
#pragma unroll
        for (int kk = 0; kk < 2; kk++) {
            short8 vf0 = (kk == 0) ? v0a : v0b;
            short8 vf1 = (kk == 0) ? v1a : v1b;
#pragma unroll
            for (int qq = 0; qq < 4; qq++) {
                short8 pf = *(const short8*)(plw + qq * 1024 + ra[kk]);
                oacc[qq][0] = MFMA16(vf0, pf, oacc[qq][0]);
                oacc[qq][1] = MFMA16(vf1, pf, oacc[qq][1]);
            }
        }
        __builtin_amdgcn_s_setprio(0);
    }

    // finalize per-lane l partials -> per-row l
#pragma unroll
    for (int qq = 0; qq < 4; qq++) {
        lrow[qq] += __shfl_xor(lrow[qq], 16, 64);
        lrow[qq] += __shfl_xor(lrow[qq], 32, 64);
    }

    // ---- stage partials (olds aliases P buffers: barrier first) ----
    __syncthreads();
    if (lhi == 0) {
#pragma unroll
        for (int qq = 0; qq < 4; qq++) {
            mlds[((w * 4 + qq) * 2 + 0) * 16 + l16] = mrow[qq];
            mlds[((w * 4 + qq) * 2 + 1) * 16 + l16] = lrow[qq];
        }
    }
#pragma unroll
    for (int qq = 0; qq < 4; qq++)
#pragma unroll
        for (int dt = 0; dt < 2; dt++)
            *(f32x4*)(olds + ((size_t)(w * 4 + qq) * 16 + l16) * 36 + dt * 16 + lhi * 4) = oacc[qq][dt];
    __syncthreads();

    // ---- merge 4 wave-partials -> un-normalized half-partial + store ----
    int d = tid & 31, q8 = tid >> 5; // q8 in 0..7
#pragma unroll
    for (int qq2 = 0; qq2 < 8; qq2++) {
        int q = q8 + qq2 * 8;        // 0..63
        int q16 = q & 15, qf = q >> 4;
        float mw[4], lw[4];
#pragma unroll
        for (int ww = 0; ww < 4; ww++) {
            mw[ww] = mlds[((ww * 4 + qf) * 2 + 0) * 16 + q16];
            lw[ww] = mlds[((ww * 4 + qf) * 2 + 1) * 16 + q16];
        }
        float mg = fmaxf(fmaxf(mw[0], mw[1]), fmaxf(mw[2], mw[3]));
        float o = 0.f, lg = 0.f;
#pragma unroll
        for (int ww = 0; ww < 4; ww++) {
            float sc = EXP2(mw[ww] - mg);
            lg += lw[ww] * sc;
            o += olds[((size_t)(ww * 4 + qf) * 16 + q16) * 36 + d] * sc;
        }
        size_t row = (size_t)(b * 2048 + m0 + q);
        po[((size_t)kvhalf * 4096 + row) * 256 + h * 32 + d] = o;
        if (d == 0) {
            float2 ml2; ml2.x = mg; ml2.y = lg;
            *(float2*)(pml + ((size_t)kvhalf * 4096 + row) * 16 + h * 2) = ml2;
        }
    }
}

// ---------------------------------------------------------------------------
// Cross-block softmax merge (2 KV halves) + residual + LayerNorm
// ---------------------------------------------------------------------------
__global__ __launch_bounds__(256) void lnmerge_kernel(
    const float* __restrict__ xin, const float* __restrict__ po,
    const float* __restrict__ pml,
    const float* __restrict__ g, const float* __restrict__ bb,
    float* __restrict__ outf, u16* __restrict__ outb)
{
    int w = threadIdx.x >> 6, lane = threadIdx.x & 63;
    int row = blockIdx.x * 4 + w;
    int h = lane >> 3;
    float m0v = pml[(size_t)row * 16 + h * 2];
    float l0v = pml[(size_t)row * 16 + h * 2 + 1];
    float m1v = pml[((size_t)4096 + row) * 16 + h * 2];
    float l1v = pml[((size_t)4096 + row) * 16 + h * 2 + 1];
    float mg = fmaxf(m0v, m1v);
    float w0 = exp2f(m0v - mg), w1 = exp2f(m1v - mg);
    float inv = 1.f / (l0v * w0 + l1v * w1);

    size_t base = (size_t)row * 256 + lane * 4;
    float4 xv = *(const float4*)(xin + base);
    float4 a0 = *(const float4*)(po + base);
    float4 a1 = *(const float4*)(po + (size_t)4096 * 256 + base);
    float s0 = xv.x + (a0.x * w0 + a1.x * w1) * inv;
    float s1 = xv.y + (a0.y * w0 + a1.y * w1) * inv;
    float s2 = xv.z + (a0.z * w0 + a1.z * w1) * inv;
    float s3 = xv.w + (a0.w * w0 + a1.w * w1) * inv;

    float sum = s0 + s1 + s2 + s3;
    float sq = s0 * s0 + s1 * s1 + s2 * s2 + s3 * s3;
#pragma unroll
    for (int off = 1; off < 64; off <<= 1) {
        sum += __shfl_xor(sum, off, 64);
        sq += __shfl_xor(sq, off, 64);
    }
    float mu = sum * (1.f / 256.f);
    float var = sq * (1.f / 256.f) - mu * mu;
    float rs = rsqrtf(var + 1e-5f);
    float4 gv = *(const float4*)(g + lane * 4);
    float4 bv = *(const float4*)(bb + lane * 4);
    float y0 = (s0 - mu) * rs * gv.x + bv.x;
    float y1 = (s1 - mu) * rs * gv.y + bv.y;
    float y2 = (s2 - mu) * rs * gv.z + bv.z;
    float y3 = (s3 - mu) * rs * gv.w + bv.w;
    float4 yo; yo.x = y0; yo.y = y1; yo.z = y2; yo.w = y3;
    *(float4*)(outf + base) = yo;
    unsigned int p0 = (unsigned int)f2bf(y0) | ((unsigned int)f2bf(y1) << 16);
    unsigned int p1 = (unsigned int)f2bf(y2) | ((unsigned int)f2bf(y3) << 16);
    uint2 pk; pk.x = p0; pk.y = p1;
    *(uint2*)(outb + base) = pk;
}

// ---------------------------------------------------------------------------
// Residual + LayerNorm (plain)
// ---------------------------------------------------------------------------
__global__ __launch_bounds__(256) void ln_kernel(
    const float* __restrict__ xin, const float* __restrict__ add,
    const float* __restrict__ g, const float* __restrict__ bb,
    float* __restrict__ outf, u16* __restrict__ outb)
{
    int w = threadIdx.x >> 6, lane = threadIdx.x & 63;
    int row = blockIdx.x * 4 + w;
    size_t base = (size_t)row * 256 + lane * 4;
    float4 xv = *(const float4*)(xin + base);
    float4 av = *(const float4*)(add + base);
    float s0 = xv.x + av.x, s1 = xv.y + av.y, s2 = xv.z + av.z, s3 = xv.w + av.w;
    float sum = s0 + s1 + s2 + s3;
    float sq = s0 * s0 + s1 * s1 + s2 * s2 + s3 * s3;
#pragma unroll
    for (int off = 1; off < 64; off <<= 1) {
        sum += __shfl_xor(sum, off, 64);
        sq += __shfl_xor(sq, off, 64);
    }
    float mu = sum * (1.f / 256.f);
    float var = sq * (1.f / 256.f) - mu * mu;
    float rs = rsqrtf(var + 1e-5f);
    float4 gv = *(const float4*)(g + lane * 4);
    float4 bv = *(const float4*)(bb + lane * 4);
    float y0 = (s0 - mu) * rs * gv.x + bv.x;
    float y1 = (s1 - mu) * rs * gv.y + bv.y;
    float y2 = (s2 - mu) * rs * gv.z + bv.z;
    float y3 = (s3 - mu) * rs * gv.w + bv.w;
    float4 yo; yo.x = y0; yo.y = y1; yo.z = y2; yo.w = y3;
    *(float4*)(outf + base) = yo;
    unsigned int p0 = (unsigned int)f2bf(y0) | ((unsigned int)f2bf(y1) << 16);
    unsigned int p1 = (unsigned int)f2bf(y2) | ((unsigned int)f2bf(y3) << 16);
    uint2 pk; pk.x = p0; pk.y = p1;
    *(uint2*)(outb + base) = pk;
}

// ---------------------------------------------------------------------------
extern "C" void kernel_launch(void* const* d_in, const int* in_sizes, int n_in,
                              void* d_out, int out_size, void* d_ws, size_t ws_size,
                              hipStream_t stream)
{
    const float* x_in   = (const float*)d_in[0];
    const float* coords = (const float*)d_in[1];
    const float* wq = (const float*)d_in[2];
    const float* bq = (const float*)d_in[3];
    const float* wk = (const float*)d_in[4];
    const float* bk = (const float*)d_in[5];
    const float* wv = (const float*)d_in[6];
    const float* bv = (const float*)d_in[7];
    const float* alpha = (const float*)d_in[8];
    const float* w1 = (const float*)d_in[9];
    const float* b1 = (const float*)d_in[10];
    const float* w2 = (const float*)d_in[11];
    const float* b2 = (const float*)d_in[12];
    const float* ln1g = (const float*)d_in[13];
    const float* ln1b = (const float*)d_in[14];
    const float* ln2g = (const float*)d_in[15];
    const float* ln2b = (const float*)d_in[16];
    float* out = (float*)d_out;

    char* ws = (char*)d_ws;
    size_t off = 0;
    auto alloc = [&](size_t bytes) -> void* {
        void* p = ws + off;
        off += (bytes + 255) & ~(size_t)255;
        return p;
    };
    float* x_f32 = (float*)alloc(4096UL * 256 * 4);
    u16*   x_bf  = (u16*)  alloc(4096UL * 256 * 2);
    u16*   qt    = (u16*)  alloc(16UL * 2048 * 32 * 2);
    u16*   ktp   = (u16*)  alloc(16UL * 2048 * 32 * 2);
    u16*   vtp   = (u16*)  alloc(16UL * 32 * 2048 * 2);
    u16*   kcoord= (u16*)  alloc(2UL * 2048 * 32 * 2);
    float* po    = (float*)alloc(2UL * 4096 * 256 * 4);
    float* pml   = (float*)alloc(2UL * 4096 * 16 * 4);
    u16*   mid   = (u16*)  alloc(4096UL * 512 * 2);
    float* ffn   = (float*)alloc(4096UL * 256 * 4);
    u16*   wqkvT = (u16*)  alloc(4UL * 768 * 256 * 2);
    u16*   w1T   = (u16*)  alloc(4UL * 512 * 256 * 2);
    u16*   w2T   = (u16*)  alloc(4UL * 256 * 512 * 2);
    float* bqkv  = (float*)alloc(4UL * 768 * 4);

    repack_kernel<<<7180, 256, 0, stream>>>(wq, wk, wv, bq, bk, bv, w1, w2,
                                            wqkvT, w1T, w2T, bqkv);
    xconv_kernel<<<4096, 256, 0, stream>>>(x_in, coords, x_f32, x_bf, kcoord);

    for (int i = 0; i < 4; i++) {
        qkvgemm_kernel<<<dim3(64, 6), 256, 0, stream>>>(
            x_bf, wqkvT + (size_t)i * 768 * 256, bqkv + i * 768, qt, ktp, vtp);
        attn_kernel<<<1024, 256, 0, stream>>>(qt, ktp, vtp, kcoord, coords, alpha, i, po, pml);
        lnmerge_kernel<<<1024, 256, 0, stream>>>(x_f32, po, pml, ln1g + i * 256, ln1b + i * 256,
                                                 x_f32, x_bf);
        gemm_relu_kernel<<<dim3(64, 4), 256, 0, stream>>>(
            x_bf, w1T + (size_t)i * 512 * 256, b1 + i * 512, mid, 4096, 512, 256);
        gemm_f32_kernel<<<dim3(64, 4), 256, 0, stream>>>(
            mid, w2T + (size_t)i * 256 * 512, b2 + i * 256, ffn, 4096, 256, 512);
        ln_kernel<<<1024, 256, 0, stream>>>(x_f32, ffn, ln2g + i * 256, ln2b + i * 256,
                                            (i == 3) ? out : x_f32, x_bf);
    }
}

// Round 20
// 295.682 us; speedup vs baseline: 1.0151x; 1.0151x over previous
//
#include <hip/hip_runtime.h>

typedef unsigned short u16;
typedef __attribute__((ext_vector_type(8))) short short8;
typedef __attribute__((ext_vector_type(4))) float f32x4;
typedef __attribute__((ext_vector_type(4))) u16 u16x4;

#define MFMA16(a, b, c) __builtin_amdgcn_mfma_f32_16x16x32_bf16(a, b, c, 0, 0, 0)
#define EXP2(x) __builtin_amdgcn_exp2f(x)

#define LOG2E 1.4426950408889634f
// q-side fold: (1/sqrt(32)) * log2(e)
#define QSCALE 0.25506038410312156f

__device__ __forceinline__ u16 f2bf(float f) {
    unsigned int u = __builtin_bit_cast(unsigned int, f);
    u += 0x7fffu + ((u >> 16) & 1u);
    return (u16)(u >> 16);
}

// ---------------------------------------------------------------------------
// repack: weights -> bf16 transposed [N][K]; q-weights pre-scaled by QSCALE
// ---------------------------------------------------------------------------
__global__ __launch_bounds__(256) void repack_kernel(
    const float* __restrict__ wq, const float* __restrict__ wk, const float* __restrict__ wv,
    const float* __restrict__ bq, const float* __restrict__ bk, const float* __restrict__ bv,
    const float* __restrict__ w1, const float* __restrict__ w2,
    u16* __restrict__ wqkvT, u16* __restrict__ w1T, u16* __restrict__ w2T,
    float* __restrict__ bqkv)
{
    long idx = (long)blockIdx.x * 256 + threadIdx.x;
    const long NQ = 4L * 768 * 256;
    const long N1 = 4L * 512 * 256;
    const long N2 = 4L * 256 * 512;
    const long NB = 4L * 768;
    if (idx < NQ) {
        long l = idx / (768 * 256); long r = idx % (768 * 256);
        long n = r / 256, k = r % 256;
        float v;
        if (n < 256)      v = wq[(l * 256 + k) * 256 + n] * QSCALE;
        else if (n < 512) v = wk[(l * 256 + k) * 256 + (n - 256)];
        else              v = wv[(l * 256 + k) * 256 + (n - 512)];
        wqkvT[idx] = f2bf(v);
    } else if ((idx -= NQ) < N1) {
        long l = idx / (512 * 256); long r = idx % (512 * 256);
        long n = r / 256, k = r % 256;
        w1T[idx] = f2bf(w1[(l * 256 + k) * 512 + n]);
    } else if ((idx -= N1) < N2) {
        long l = idx / (256 * 512); long r = idx % (256 * 512);
        long n = r / 512, k = r % 512;
        w2T[idx] = f2bf(w2[(l * 512 + k) * 256 + n]);
    } else if ((idx -= N2) < NB) {
        long l = idx / 768; long n = idx % 768;
        float v = (n < 256) ? bq[l * 256 + n] * QSCALE
                : (n < 512) ? bk[l * 256 + (n - 256)]
                            : bv[l * 256 + (n - 512)];
        bqkv[l * 768 + n] = v;
    }
}

// ---------------------------------------------------------------------------
// x convert: fp32 master + bf16 copy; also build kcoord rows (layer-indep):
// kcoord[b][n][32] bf16 = {LOG2E*c0, LOG2E*c1, LOG2E*c2, 0...} (zero-padded)
// ---------------------------------------------------------------------------
__global__ __launch_bounds__(256) void xconv_kernel(
    const float* __restrict__ xin, const float* __restrict__ coords,
    float* __restrict__ xf, u16* __restrict__ xb, u16* __restrict__ kcoord)
{
    long idx = (long)blockIdx.x * 256 + threadIdx.x;
    if (idx < 4096L * 256) {
        float v = xin[idx];
        xf[idx] = v;
        xb[idx] = f2bf(v);
    }
    if (idx < 4096) {
        const float* c = coords + idx * 3;
        u16 r0 = f2bf(c[0] * LOG2E), r1 = f2bf(c[1] * LOG2E), r2 = f2bf(c[2] * LOG2E);
        uint4 lo; lo.x = (unsigned)r0 | ((unsigned)r1 << 16); lo.y = (unsigned)r2; lo.z = 0; lo.w = 0;
        uint4 z4; z4.x = 0; z4.y = 0; z4.z = 0; z4.w = 0;
        uint4* dst = (uint4*)(kcoord + idx * 32);
        dst[0] = lo; dst[1] = z4; dst[2] = z4; dst[3] = z4;
    }
}

// ---------------------------------------------------------------------------
// QKV GEMM: A[4096,256]@BT[768,256]^T + bias -> packed per-head outputs:
//   qt/kt[bh][2048][32], vt[bh][32][2048]   (bh = b*8+h)
// Wave tile 32x64 (2x4 frags, 6 loads : 8 MFMA). Block 64x128. Grid (64,6).
// ---------------------------------------------------------------------------
__global__ __launch_bounds__(256) void qkvgemm_kernel(
    const u16* __restrict__ A, const u16* __restrict__ BT,
    const float* __restrict__ bias,
    u16* __restrict__ qt, u16* __restrict__ kt, u16* __restrict__ vt)
{
    const int K = 256;
    int w = threadIdx.x >> 6, lane = threadIdx.x & 63;
    int wr = w >> 1, wc = w & 1;
    int m0 = blockIdx.x * 64 + wr * 32;
    int n0 = blockIdx.y * 128 + wc * 64;
    int l16 = lane & 15, lhi = lane >> 4;

    f32x4 acc[2][4];
#pragma unroll
    for (int i = 0; i < 2; i++)
#pragma unroll
        for (int j = 0; j < 4; j++) acc[i][j] = (f32x4){0.f, 0.f, 0.f, 0.f};

    const u16* Ap = A + (size_t)(m0 + l16) * K + lhi * 8;
    const u16* Bp = BT + (size_t)(n0 + l16) * K + lhi * 8;

#pragma unroll 4
    for (int k = 0; k < K; k += 32) {
        short8 a0 = *(const short8*)(Ap + k);
        short8 a1 = *(const short8*)(Ap + (size_t)16 * K + k);
        short8 b[4];
#pragma unroll
        for (int j = 0; j < 4; j++) b[j] = *(const short8*)(Bp + (size_t)(j * 16) * K + k);
#pragma unroll
        for (int j = 0; j < 4; j++) {
            acc[0][j] = MFMA16(a0, b[j], acc[0][j]);
            acc[1][j] = MFMA16(a1, b[j], acc[1][j]);
        }
    }

#pragma unroll
    for (int i = 0; i < 2; i++)
#pragma unroll
        for (int j = 0; j < 4; j++) {
            int n = n0 + j * 16 + l16;
            float bs = bias[n];
            int sect = n >> 8;          // 0:q 1:k 2:v
            int h = (n >> 5) & 7;
            int d = n & 31;
            int m = m0 + i * 16 + lhi * 4;
            int b_ = m >> 11, mseq = m & 2047;
            if (sect < 2) {
                u16* dst = (sect == 0 ? qt : kt) + ((size_t)(b_ * 8 + h) * 2048 + mseq) * 32 + d;
#pragma unroll
                for (int r = 0; r < 4; r++) dst[(size_t)r * 32] = f2bf(acc[i][j][r] + bs);
            } else {
                u16x4 pk;
#pragma unroll
                for (int r = 0; r < 4; r++) pk[r] = f2bf(acc[i][j][r] + bs);
                *(u16x4*)(vt + ((size_t)(b_ * 8 + h) * 32 + d) * 2048 + mseq) = pk;
            }
        }
}

// ---------------------------------------------------------------------------
// FFN1 GEMM: relu(A@BT^T + bias), bf16 out. Wave 32x64, block 64x128.
// Grid (64, 4) for N=512.
// ---------------------------------------------------------------------------
__global__ __launch_bounds__(256) void gemm_relu_kernel(
    const u16* __restrict__ A, const u16* __restrict__ BT,
    const float* __restrict__ bias, u16* __restrict__ outp,
    int M, int N, int K)
{
    int w = threadIdx.x >> 6, lane = threadIdx.x & 63;
    int wr = w >> 1, wc = w & 1;
    int m0 = blockIdx.x * 64 + wr * 32;
    int n0 = blockIdx.y * 128 + wc * 64;
    int l16 = lane & 15, lhi = lane >> 4;

    f32x4 acc[2][4];
#pragma unroll
    for (int i = 0; i < 2; i++)
#pragma unroll
        for (int j = 0; j < 4; j++) acc[i][j] = (f32x4){0.f, 0.f, 0.f, 0.f};

    const u16* Ap = A + (size_t)(m0 + l16) * K + lhi * 8;
    const u16* Bp = BT + (size_t)(n0 + l16) * K + lhi * 8;

#pragma unroll 4
    for (int k = 0; k < K; k += 32) {
        short8 a0 = *(const short8*)(Ap + k);
        short8 a1 = *(const short8*)(Ap + (size_t)16 * K + k);
        short8 b[4];
#pragma unroll
        for (int j = 0; j < 4; j++) b[j] = *(const short8*)(Bp + (size_t)(j * 16) * K + k);
#pragma unroll
        for (int j = 0; j < 4; j++) {
            acc[0][j] = MFMA16(a0, b[j], acc[0][j]);
            acc[1][j] = MFMA16(a1, b[j], acc[1][j]);
        }
    }

#pragma unroll
    for (int i = 0; i < 2; i++)
#pragma unroll
        for (int j = 0; j < 4; j++) {
            int n = n0 + j * 16 + l16;
            float bs = bias[n];
#pragma unroll
            for (int r = 0; r < 4; r++) {
                int m = m0 + i * 16 + lhi * 4 + r;
                outp[(size_t)m * N + n] = f2bf(fmaxf(acc[i][j][r] + bs, 0.f));
            }
        }
}

// ---------------------------------------------------------------------------
// FFN2 GEMM: C = A@BT^T + bias, f32 out. Block 64x64 (4 waves 32x32).
// ---------------------------------------------------------------------------
__global__ __launch_bounds__(256) void gemm_f32_kernel(
    const u16* __restrict__ A, const u16* __restrict__ BT,
    const float* __restrict__ bias, float* __restrict__ outp,
    int M, int N, int K)
{
    int w = threadIdx.x >> 6, lane = threadIdx.x & 63;
    int wr = w >> 1, wc = w & 1;
    int m0 = blockIdx.x * 64 + wr * 32;
    int n0 = blockIdx.y * 64 + wc * 32;
    int l16 = lane & 15, lhi = lane >> 4;

    f32x4 acc[2][2];
#pragma unroll
    for (int i = 0; i < 2; i++)
#pragma unroll
        for (int j = 0; j < 2; j++) acc[i][j] = (f32x4){0.f, 0.f, 0.f, 0.f};

    const u16* Ap = A + (size_t)(m0 + l16) * K + lhi * 8;
    const u16* Bp = BT + (size_t)(n0 + l16) * K + lhi * 8;

#pragma unroll 4
    for (int k = 0; k < K; k += 32) {
        short8 a0 = *(const short8*)(Ap + k);
        short8 a1 = *(const short8*)(Ap + (size_t)16 * K + k);
        short8 b0 = *(const short8*)(Bp + k);
        short8 b1 = *(const short8*)(Bp + (size_t)16 * K + k);
        acc[0][0] = MFMA16(a0, b0, acc[0][0]);
        acc[0][1] = MFMA16(a0, b1, acc[0][1]);
        acc[1][0] = MFMA16(a1, b0, acc[1][0]);
        acc[1][1] = MFMA16(a1, b1, acc[1][1]);
    }

#pragma unroll
    for (int i = 0; i < 2; i++)
#pragma unroll
        for (int j = 0; j < 2; j++) {
            int n = n0 + j * 16 + l16;
            float bs = bias[n];
#pragma unroll
            for (int r = 0; r < 4; r++) {
                int m = m0 + i * 16 + lhi * 4 + r;
                outp[(size_t)m * N + n] = acc[i][j][r] + bs;
            }
        }
}

// ---------------------------------------------------------------------------
// Flash attention, 4 Q-fragments (64 q-rows/block) sharing every K/khi/V
// load: 48 MFMAs per 12-load round (2x R12's density). Grid 1024 =
// 16 bh x 32 qtiles x 2 kvhalf -> exactly 4 blocks/CU (38KB LDS), whole
// grid resident. Swapped-QK^T, ballot-gated defer-max, per-lane l partials.
// ---------------------------------------------------------------------------
__global__ __launch_bounds__(256, 2) void attn_kernel(
    const u16* __restrict__ qt, const u16* __restrict__ kt, const u16* __restrict__ vt,
    const u16* __restrict__ kcoord, const float* __restrict__ coords,
    const float* __restrict__ alpha, int layer,
    float* __restrict__ po, float* __restrict__ pml)
{
    int tid = threadIdx.x;
    int w = tid >> 6, lane = tid & 63;
    int flat = blockIdx.x;
    int bh = (flat & 7) | (((flat >> 3) & 1) << 3);
    int b = bh >> 3, h = bh & 7;
    int m0 = ((flat >> 4) & 31) * 64;
    int kvhalf = flat >> 9;
    int l16 = lane & 15, lhi = lane >> 4;

    // smem: [0,32768) = per-(wave,qq) P buffers u16[16][1024] (2KB each),
    //       aliased post-barrier as float olds[16][16][36] (36864 B)
    //       [36864, 38912) = float mlds[16][2][16]
    __shared__ __align__(16) char smem[36864 + 2048];
    float* olds = (float*)smem;
    float* mlds = (float*)(smem + 36864);
    u16* plbase = (u16*)smem;

    const u16* qbase = qt + (size_t)bh * 2048 * 32;
    float al = alpha[layer];
    short8 qlo[4], qhi[4];
#pragma unroll
    for (int qq = 0; qq < 4; qq++) {
        qlo[qq] = *(const short8*)(qbase + (size_t)(m0 + qq * 16 + l16) * 32 + lhi * 8);
        short8 z = {0, 0, 0, 0, 0, 0, 0, 0};
        qhi[qq] = z;
        if (lhi == 0) {
            const float* c = coords + (size_t)(b * 2048 + m0 + qq * 16 + l16) * 3;
            qhi[qq][0] = (short)f2bf(c[0] * al);
            qhi[qq][1] = (short)f2bf(c[1] * al);
            qhi[qq][2] = (short)f2bf(c[2] * al);
        }
    }

    f32x4 oacc[4][2];
#pragma unroll
    for (int qq = 0; qq < 4; qq++)
#pragma unroll
        for (int dt = 0; dt < 2; dt++) oacc[qq][dt] = (f32x4){0.f, 0.f, 0.f, 0.f};
    float mrow[4] = {-1e30f, -1e30f, -1e30f, -1e30f};
    float lrow[4] = {0.f, 0.f, 0.f, 0.f};

    int nstart = kvhalf * 1024 + w * 256;   // 256 KV cols per wave = 4 x 64

    unsigned kidx = ((unsigned)(bh * 2048 + nstart + l16) << 5) + lhi * 8;
    unsigned cidx = ((unsigned)(b * 2048 + nstart + l16) << 5) + lhi * 8;
    unsigned vidxA = ((unsigned)(bh * 32 + l16) << 11) + nstart + lhi * 8;
    unsigned vidxB = vidxA + (16u << 11);

    int hb = lhi >> 1, s7 = l16 & 7, lo4 = (lhi & 1) * 4;
    int wb = l16 * 64;
    int wa[4], ra[2];
#pragma unroll
    for (int t = 0; t < 4; t++) wa[t] = wb + (((((t << 1) | hb)) ^ s7) << 3) + lo4;
#pragma unroll
    for (int kk = 0; kk < 2; kk++) ra[kk] = wb + ((((kk << 2) | lhi) ^ s7) << 3);

    u16* plw = plbase + w * 4096;           // 4 qq buffers of 1024 u16 each

#pragma unroll
    for (int nbi = 0; nbi < 4; nbi++) {
        // tile loads (shared across all 4 Q-fragments)
        short8 klo[4], khi[4];
#pragma unroll
        for (int t = 0; t < 4; t++) klo[t] = *(const short8*)(kt + kidx + t * 512);
#pragma unroll
        for (int t = 0; t < 4; t++) khi[t] = *(const short8*)(kcoord + cidx + t * 512);
        kidx += 2048; cidx += 2048;
        short8 v0a = *(const short8*)(vt + vidxA);
        short8 v0b = *(const short8*)(vt + vidxA + 32);
        short8 v1a = *(const short8*)(vt + vidxB);
        short8 v1b = *(const short8*)(vt + vidxB + 32);
        vidxA += 64; vidxB += 64;

#pragma unroll
        for (int qq = 0; qq < 4; qq++) {
            f32x4 s[4];
#pragma unroll
            for (int t = 0; t < 4; t++) {
                f32x4 z = (f32x4){0.f, 0.f, 0.f, 0.f};
                z = MFMA16(klo[t], qlo[qq], z);
                s[t] = MFMA16(khi[t], qhi[qq], z);
            }
            float lm = -1e30f;
#pragma unroll
            for (int t = 0; t < 4; t++) {
                float a = fmaxf(fmaxf(s[t][0], s[t][1]), fmaxf(s[t][2], s[t][3]));
                lm = fmaxf(lm, a);
            }
            if (!__all(lm <= mrow[qq] + 8.f)) {
                float tm = fmaxf(lm, __shfl_xor(lm, 16, 64));
                tm = fmaxf(tm, __shfl_xor(tm, 32, 64));
                float mnew = fmaxf(mrow[qq], tm);
                float corr = EXP2(mrow[qq] - mnew);
                mrow[qq] = mnew;
#pragma unroll
                for (int dt = 0; dt < 2; dt++)
#pragma unroll
                    for (int r = 0; r < 4; r++) oacc[qq][dt][r] *= corr;
                lrow[qq] *= corr;
            }

            float rs = 0.f;
#pragma unroll
            for (int t = 0; t < 4; t++) {
#pragma unroll
                for (int r = 0; r < 4; r++) s[t][r] = EXP2(s[t][r] - mrow[qq]);
                rs += (s[t][0] + s[t][1]) + (s[t][2] + s[t][3]);
            }
            lrow[qq] += rs;  // per-lane partial; cross-lane reduce at wave end

            u16* pl = plw + qq * 1024;
#pragma unroll
            for (int t = 0; t < 4; t++) {
                unsigned p0, p1;
                asm("v_cvt_pk_bf16_f32 %0, %1, %2" : "=v"(p0) : "v"(s[t][0]), "v"(s[t][1]));
                asm("v_cvt_pk_bf16_f32 %0, %1, %2" : "=v"(p1) : "v"(s[t][2]), "v"(s[t][3]));
                uint2 val; val.x = p0; val.y = p1;
                *(uint2*)(pl + wa[t]) = val;
            }
        }

        // PV: out^T[d][q] += V^T[d][n] * P^T[n][q]; V shared across qq
#pragma unroll
        for (int kk = 0; kk < 2; kk++) {
            short8 vf0 = (kk == 0) ? v0a : v0b;
            short8 vf1 = (kk == 0) ? v1a : v1b;
#pragma unroll
            for (int qq = 0; qq < 4; qq++) {
                short8 pf = *(const short8*)(plw + qq * 1024 + ra[kk]);
                oacc[qq][0] = MFMA16(vf0, pf, oacc[qq][0]);
                oacc[qq][1] = MFMA16(vf1, pf, oacc[qq][1]);
            }
        }
    }

    // finalize per-lane l partials -> per-row l
#pragma unroll
    for (int qq = 0; qq < 4; qq++) {
        lrow[qq] += __shfl_xor(lrow[qq], 16, 64);
        lrow[qq] += __shfl_xor(lrow[qq], 32, 64);
    }

    // ---- stage partials (olds aliases P buffers: barrier first) ----
    __syncthreads();
    if (lhi == 0) {
#pragma unroll
        for (int qq = 0; qq < 4; qq++) {
            mlds[((w * 4 + qq) * 2 + 0) * 16 + l16] = mrow[qq];
            mlds[((w * 4 + qq) * 2 + 1) * 16 + l16] = lrow[qq];
        }
    }
#pragma unroll
    for (int qq = 0; qq < 4; qq++)
#pragma unroll
        for (int dt = 0; dt < 2; dt++)
            *(f32x4*)(olds + ((size_t)(w * 4 + qq) * 16 + l16) * 36 + dt * 16 + lhi * 4) = oacc[qq][dt];
    __syncthreads();

    // ---- merge 4 wave-partials -> un-normalized half-partial + store ----
    int d = tid & 31, q8 = tid >> 5; // q8 in 0..7
#pragma unroll
    for (int qq2 = 0; qq2 < 8; qq2++) {
        int q = q8 + qq2 * 8;        // 0..63
        int q16 = q & 15, qf = q >> 4;
        float mw[4], lw[4];
#pragma unroll
        for (int ww = 0; ww < 4; ww++) {
            mw[ww] = mlds[((ww * 4 + qf) * 2 + 0) * 16 + q16];
            lw[ww] = mlds[((ww * 4 + qf) * 2 + 1) * 16 + q16];
        }
        float mg = fmaxf(fmaxf(mw[0], mw[1]), fmaxf(mw[2], mw[3]));
        float o = 0.f, lg = 0.f;
#pragma unroll
        for (int ww = 0; ww < 4; ww++) {
            float sc = EXP2(mw[ww] - mg);
            lg += lw[ww] * sc;
            o += olds[((size_t)(ww * 4 + qf) * 16 + q16) * 36 + d] * sc;
        }
        size_t row = (size_t)(b * 2048 + m0 + q);
        po[((size_t)kvhalf * 4096 + row) * 256 + h * 32 + d] = o;
        if (d == 0) {
            float2 ml2; ml2.x = mg; ml2.y = lg;
            *(float2*)(pml + ((size_t)kvhalf * 4096 + row) * 16 + h * 2) = ml2;
        }
    }
}

// ---------------------------------------------------------------------------
// Cross-block softmax merge (2 KV halves) + residual + LayerNorm
// ---------------------------------------------------------------------------
__global__ __launch_bounds__(256) void lnmerge_kernel(
    const float* __restrict__ xin, const float* __restrict__ po,
    const float* __restrict__ pml,
    const float* __restrict__ g, const float* __restrict__ bb,
    float* __restrict__ outf, u16* __restrict__ outb)
{
    int w = threadIdx.x >> 6, lane = threadIdx.x & 63;
    int row = blockIdx.x * 4 + w;
    int h = lane >> 3;
    float m0v = pml[(size_t)row * 16 + h * 2];
    float l0v = pml[(size_t)row * 16 + h * 2 + 1];
    float m1v = pml[((size_t)4096 + row) * 16 + h * 2];
    float l1v = pml[((size_t)4096 + row) * 16 + h * 2 + 1];
    float mg = fmaxf(m0v, m1v);
    float w0 = exp2f(m0v - mg), w1 = exp2f(m1v - mg);
    float inv = 1.f / (l0v * w0 + l1v * w1);

    size_t base = (size_t)row * 256 + lane * 4;
    float4 xv = *(const float4*)(xin + base);
    float4 a0 = *(const float4*)(po + base);
    float4 a1 = *(const float4*)(po + (size_t)4096 * 256 + base);
    float s0 = xv.x + (a0.x * w0 + a1.x * w1) * inv;
    float s1 = xv.y + (a0.y * w0 + a1.y * w1) * inv;
    float s2 = xv.z + (a0.z * w0 + a1.z * w1) * inv;
    float s3 = xv.w + (a0.w * w0 + a1.w * w1) * inv;

    float sum = s0 + s1 + s2 + s3;
    float sq = s0 * s0 + s1 * s1 + s2 * s2 + s3 * s3;
#pragma unroll
    for (int off = 1; off < 64; off <<= 1) {
        sum += __shfl_xor(sum, off, 64);
        sq += __shfl_xor(sq, off, 64);
    }
    float mu = sum * (1.f / 256.f);
    float var = sq * (1.f / 256.f) - mu * mu;
    float rs = rsqrtf(var + 1e-5f);
    float4 gv = *(const float4*)(g + lane * 4);
    float4 bv = *(const float4*)(bb + lane * 4);
    float y0 = (s0 - mu) * rs * gv.x + bv.x;
    float y1 = (s1 - mu) * rs * gv.y + bv.y;
    float y2 = (s2 - mu) * rs * gv.z + bv.z;
    float y3 = (s3 - mu) * rs * gv.w + bv.w;
    float4 yo; yo.x = y0; yo.y = y1; yo.z = y2; yo.w = y3;
    *(float4*)(outf + base) = yo;
    unsigned int p0 = (unsigned int)f2bf(y0) | ((unsigned int)f2bf(y1) << 16);
    unsigned int p1 = (unsigned int)f2bf(y2) | ((unsigned int)f2bf(y3) << 16);
    uint2 pk; pk.x = p0; pk.y = p1;
    *(uint2*)(outb + base) = pk;
}

// ---------------------------------------------------------------------------
// Residual + LayerNorm (plain)
// ---------------------------------------------------------------------------
__global__ __launch_bounds__(256) void ln_kernel(
    const float* __restrict__ xin, const float* __restrict__ add,
    const float* __restrict__ g, const float* __restrict__ bb,
    float* __restrict__ outf, u16* __restrict__ outb)
{
    int w = threadIdx.x >> 6, lane = threadIdx.x & 63;
    int row = blockIdx.x * 4 + w;
    size_t base = (size_t)row * 256 + lane * 4;
    float4 xv = *(const float4*)(xin + base);
    float4 av = *(const float4*)(add + base);
    float s0 = xv.x + av.x, s1 = xv.y + av.y, s2 = xv.z + av.z, s3 = xv.w + av.w;
    float sum = s0 + s1 + s2 + s3;
    float sq = s0 * s0 + s1 * s1 + s2 * s2 + s3 * s3;
#pragma unroll
    for (int off = 1; off < 64; off <<= 1) {
        sum += __shfl_xor(sum, off, 64);
        sq += __shfl_xor(sq, off, 64);
    }
    float mu = sum * (1.f / 256.f);
    float var = sq * (1.f / 256.f) - mu * mu;
    float rs = rsqrtf(var + 1e-5f);
    float4 gv = *(const float4*)(g + lane * 4);
    float4 bv = *(const float4*)(bb + lane * 4);
    float y0 = (s0 - mu) * rs * gv.x + bv.x;
    float y1 = (s1 - mu) * rs * gv.y + bv.y;
    float y2 = (s2 - mu) * rs * gv.z + bv.z;
    float y3 = (s3 - mu) * rs * gv.w + bv.w;
    float4 yo; yo.x = y0; yo.y = y1; yo.z = y2; yo.w = y3;
    *(float4*)(outf + base) = yo;
    unsigned int p0 = (unsigned int)f2bf(y0) | ((unsigned int)f2bf(y1) << 16);
    unsigned int p1 = (unsigned int)f2bf(y2) | ((unsigned int)f2bf(y3) << 16);
    uint2 pk; pk.x = p0; pk.y = p1;
    *(uint2*)(outb + base) = pk;
}

// ---------------------------------------------------------------------------
extern "C" void kernel_launch(void* const* d_in, const int* in_sizes, int n_in,
                              void* d_out, int out_size, void* d_ws, size_t ws_size,
                              hipStream_t stream)
{
    const float* x_in   = (const float*)d_in[0];
    const float* coords = (const float*)d_in[1];
    const float* wq = (const float*)d_in[2];
    const float* bq = (const float*)d_in[3];
    const float* wk = (const float*)d_in[4];
    const float* bk = (const float*)d_in[5];
    const float* wv = (const float*)d_in[6];
    const float* bv = (const float*)d_in[7];
    const float* alpha = (const float*)d_in[8];
    const float* w1 = (const float*)d_in[9];
    const float* b1 = (const float*)d_in[10];
    const float* w2 = (const float*)d_in[11];
    const float* b2 = (const float*)d_in[12];
    const float* ln1g = (const float*)d_in[13];
    const float* ln1b = (const float*)d_in[14];
    const float* ln2g = (const float*)d_in[15];
    const float* ln2b = (const float*)d_in[16];
    float* out = (float*)d_out;

    char* ws = (char*)d_ws;
    size_t off = 0;
    auto alloc = [&](size_t bytes) -> void* {
        void* p = ws + off;
        off += (bytes + 255) & ~(size_t)255;
        return p;
    };
    float* x_f32 = (float*)alloc(4096UL * 256 * 4);
    u16*   x_bf  = (u16*)  alloc(4096UL * 256 * 2);
    u16*   qt    = (u16*)  alloc(16UL * 2048 * 32 * 2);
    u16*   ktp   = (u16*)  alloc(16UL * 2048 * 32 * 2);
    u16*   vtp   = (u16*)  alloc(16UL * 32 * 2048 * 2);
    u16*   kcoord= (u16*)  alloc(2UL * 2048 * 32 * 2);
    float* po    = (float*)alloc(2UL * 4096 * 256 * 4);
    float* pml   = (float*)alloc(2UL * 4096 * 16 * 4);
    u16*   mid   = (u16*)  alloc(4096UL * 512 * 2);
    float* ffn   = (float*)alloc(4096UL * 256 * 4);
    u16*   wqkvT = (u16*)  alloc(4UL * 768 * 256 * 2);
    u16*   w1T   = (u16*)  alloc(4UL * 512 * 256 * 2);
    u16*   w2T   = (u16*)  alloc(4UL * 256 * 512 * 2);
    float* bqkv  = (float*)alloc(4UL * 768 * 4);

    repack_kernel<<<7180, 256, 0, stream>>>(wq, wk, wv, bq, bk, bv, w1, w2,
                                            wqkvT, w1T, w2T, bqkv);
    xconv_kernel<<<4096, 256, 0, stream>>>(x_in, coords, x_f32, x_bf, kcoord);

    for (int i = 0; i < 4; i++) {
        qkvgemm_kernel<<<dim3(64, 6), 256, 0, stream>>>(
            x_bf, wqkvT + (size_t)i * 768 * 256, bqkv + i * 768, qt, ktp, vtp);
        attn_kernel<<<1024, 256, 0, stream>>>(qt, ktp, vtp, kcoord, coords, alpha, i, po, pml);
        lnmerge_kernel<<<1024, 256, 0, stream>>>(x_f32, po, pml, ln1g + i * 256, ln1b + i * 256,
                                                 x_f32, x_bf);
        gemm_relu_kernel<<<dim3(64, 4), 256, 0, stream>>>(
            x_bf, w1T + (size_t)i * 512 * 256, b1 + i * 512, mid, 4096, 512, 256);
        gemm_f32_kernel<<<dim3(64, 4), 256, 0, stream>>>(
            mid, w2T + (size_t)i * 256 * 512, b2 + i * 256, ffn, 4096, 256, 512);
        ln_kernel<<<1024, 256, 0, stream>>>(x_f32, ffn, ln2g + i * 256, ln2b + i * 256,
                                            (i == 3) ? out : x_f32, x_bf);
    }
}